// Round 15
// baseline (986.621 us; speedup 1.0000x reference)
//
#include <hip/hip_runtime.h>
#include <hip/hip_bf16.h>
#include <math.h>

#define NN 20000
#define EE 640000
#define HH 128
#define LL 12
#define DOUT_ 16
#define EPS_ 1e-7f
#define LN_EPS_ 1e-5f

typedef unsigned short u16;
typedef unsigned int u32;
typedef __attribute__((ext_vector_type(8))) short bf16x8;
typedef __attribute__((ext_vector_type(4))) float f32x4;

__device__ inline u16 bf16_rne(float v) {
  u32 u = __float_as_uint(v);
  return (u16)((u + 0x7FFFu + ((u >> 16) & 1u)) >> 16);
}
__device__ inline float bf16_tof(u16 h) { return __uint_as_float(((u32)h) << 16); }

// ---------------- CSR build ----------------
__global__ __launch_bounds__(256) void hist_kernel(const int* __restrict__ dst, int* __restrict__ deg) {
  int e = blockIdx.x * 256 + threadIdx.x;
  if (e < EE) atomicAdd(&deg[dst[e]], 1);
}

__global__ __launch_bounds__(1024) void scan_kernel(const int* __restrict__ deg, int* __restrict__ off,
                                                    int* __restrict__ cur) {
  __shared__ int part[1024];
  int tid = threadIdx.x;
  const int CH = (NN + 1023) >> 10;   // 20
  int base = tid * CH;
  int s = 0;
  for (int j = 0; j < CH; ++j) { int i = base + j; if (i < NN) s += deg[i]; }
  part[tid] = s;
  __syncthreads();
  for (int d = 1; d < 1024; d <<= 1) {
    int v = (tid >= d) ? part[tid - d] : 0;
    __syncthreads();
    part[tid] += v;
    __syncthreads();
  }
  int run = part[tid] - s;  // exclusive prefix
  for (int j = 0; j < CH; ++j) {
    int i = base + j;
    if (i < NN) { off[i] = run; cur[i] = run; run += deg[i]; }
  }
  if (tid == 1023) off[NN] = part[1023];
}

__global__ __launch_bounds__(256) void scatter_kernel(const int* __restrict__ src, const int* __restrict__ dst,
                                                      const float4* __restrict__ ea, int* __restrict__ cur,
                                                      int* __restrict__ srcs, float4* __restrict__ ea4) {
  int e = blockIdx.x * 256 + threadIdx.x;
  if (e >= EE) return;
  int d = dst[e];
  int p = atomicAdd(&cur[d], 1);
  srcs[p] = src[e];
  ea4[p] = ea[e];
}

// ---------------- weight pack: fp32 [L][K][N] -> bf16 (hi only) MFMA-fragment order ----------------
// layout: [l][chunk][tI(N/16)][ks2(KSC)][lane(64)][j(8)]; k = (chunk*KSC+ks2)*32 + (lane>>4)*8 + j
__global__ __launch_bounds__(256) void wpack_kernel(const float* __restrict__ w, u16* __restrict__ dh,
                                                    int K, int N, int KSC) {
  int fid = blockIdx.x * 256 + threadIdx.x;
  int perL = (K * N) >> 3;
  if (fid >= LL * perL) return;
  int l = fid / perL, r = fid % perL;
  int lane = r & 63;
  int r2 = r >> 6;
  int ks2 = r2 % KSC; r2 /= KSC;
  int NT = N >> 4;
  int tI = r2 % NT;
  int chunk = r2 / NT;
  int c16 = lane & 15, kg = lane >> 4;
  int n = tI * 16 + c16;
  int k0 = (chunk * KSC + ks2) * 32 + kg * 8;
  const float* ws = w + (size_t)l * K * N;
  u16* oh = dh + (size_t)fid * 8;
  #pragma unroll
  for (int j = 0; j < 8; ++j) {
    oh[j] = bf16_rne(ws[(size_t)(k0 + j) * N + n]);
  }
}

// ---------------- encoder: h fp32 + hb bf16 plane ----------------
__global__ __launch_bounds__(256) void encoder_kernel(const float* __restrict__ x, const float* __restrict__ w,
                                                      const float* __restrict__ b, float* __restrict__ h,
                                                      u16* __restrict__ hb) {
  int id = blockIdx.x * 256 + threadIdx.x;
  if (id >= NN * 64) return;
  int n = id >> 6, cp = id & 63;
  int c0 = cp * 2;
  float x0 = x[n*3+0], x1 = x[n*3+1], x2 = x[n*3+2];
  float vx = b[c0]   + x0*w[c0]   + x1*w[HH+c0]   + x2*w[2*HH+c0];
  float vy = b[c0+1] + x0*w[c0+1] + x1*w[HH+c0+1] + x2*w[2*HH+c0+1];
  *(float2*)&h[(size_t)n*HH + c0] = make_float2(vx, vy);
  *(u32*)&hb[(size_t)n*HH + c0] = (u32)bf16_rne(vx) | ((u32)bf16_rne(vy) << 16);
}

// ---------------- GENConv aggregation: wave per dst node, predicated tail ----------------
// Round-12 structure (separate srcs/ea4 arrays, UF=8 batches), but the scalar tail
// is folded into the batches: OOR edges clamp the load index to e1-1 and add
// bias=-1e38 inside the exp argument -> p = exp2(-1e38) = 0. Also folds log2e
// into the temperature (exp2f(fma(m,tl,bias)) == exp(m*t) masked).
__global__ __launch_bounds__(256) void conv_kernel(const float* __restrict__ hn,
                                                   const u16* __restrict__ hb,
                                                   const int* __restrict__ off,
                                                   const int* __restrict__ srcs, const float4* __restrict__ ea4,
                                                   const float* __restrict__ eew, const float* __restrict__ eeb,
                                                   const float* __restrict__ t, int layer,
                                                   u16* __restrict__ tmpH, u16* __restrict__ tmpL) {
  int wid = blockIdx.x * 4 + (threadIdx.x >> 6);
  int lane = threadIdx.x & 63;
  if (wid >= NN) return;
  int c0 = lane * 2;
  float tl = t[layer] * 1.44269504089f;
  float w0x = eew[c0],      w0y = eew[c0+1];
  float w1x = eew[HH+c0],   w1y = eew[HH+c0+1];
  float w2x = eew[2*HH+c0], w2y = eew[2*HH+c0+1];
  float w3x = eew[3*HH+c0], w3y = eew[3*HH+c0+1];
  float bx = eeb[c0], by = eeb[c0+1];
  int e0 = off[wid], e1 = off[wid+1];
  float2 hd = *(const float2*)&hn[(size_t)wid*HH + c0];
  float den0 = 0.f, den1 = 0.f, num0 = 0.f, num1 = 0.f;

  const int UF = 8;
  for (int e = e0; e < e1; e += UF) {
    int si[UF]; float4 av[UF]; float bias[UF];
    #pragma unroll
    for (int u = 0; u < UF; ++u) {
      int ee = e + u;
      bool ok = ee < e1;
      int idx = ok ? ee : (e1 - 1);
      si[u] = srcs[idx];
      av[u] = ea4[idx];
      bias[u] = ok ? 0.f : -1e38f;
    }
    u32 hv[UF];
    #pragma unroll
    for (int u = 0; u < UF; ++u) hv[u] = *(const u32*)&hb[((u32)si[u] << 7) + c0];
    #pragma unroll
    for (int u = 0; u < UF; ++u) {
      float hx = bf16_tof((u16)(hv[u] & 0xffffu));
      float hy = bf16_tof((u16)(hv[u] >> 16));
      float eax = fmaf(av[u].w, w3x, fmaf(av[u].z, w2x, fmaf(av[u].y, w1x, fmaf(av[u].x, w0x, bx))));
      float eay = fmaf(av[u].w, w3y, fmaf(av[u].z, w2y, fmaf(av[u].y, w1y, fmaf(av[u].x, w0y, by))));
      float m0 = fmaxf(hx + eax, 0.f) + EPS_;
      float m1 = fmaxf(hy + eay, 0.f) + EPS_;
      float p0 = exp2f(fmaf(m0, tl, bias[u]));
      float p1 = exp2f(fmaf(m1, tl, bias[u]));
      den0 += p0; den1 += p1;
      num0 = fmaf(m0, p0, num0);
      num1 = fmaf(m1, p1, num1);
    }
  }
  float v0 = num0 / (den0 + 1e-16f) + hd.x;
  float v1 = num1 / (den1 + 1e-16f) + hd.y;
  u16 h0 = bf16_rne(v0), h1 = bf16_rne(v1);
  u16 l0 = bf16_rne(v0 - bf16_tof(h0)), l1 = bf16_rne(v1 - bf16_tof(h1));
  *(u32*)&tmpH[(size_t)wid*HH + c0] = (u32)h0 | ((u32)h1 << 16);
  *(u32*)&tmpL[(size_t)wid*HH + c0] = (u32)l0 | ((u32)l1 << 16);
}

// ---------------- fused MLP: GEMM1 + LN(256) + ReLU -> LDS -> GEMM2 + residual + LN(128) ----------------
// block = 16 rows, 4 waves. GEMM1: wave owns 64 cols, 2 MFMA per frag (A hi/lo split x plain-bf16 W1).
// U tile (16x256 bf16) lives in LDS only. GEMM2: wave owns 32 cols, 1 MFMA per frag
// (plain U x plain-bf16 W2). W planes read direct from L2 (packed fragment order).
__global__ __launch_bounds__(256) void mlp_fused(const u16* __restrict__ Ah, const u16* __restrict__ Al,
                                                 const u16* __restrict__ B1h,
                                                 const float* __restrict__ b1,
                                                 const float* __restrict__ g1, const float* __restrict__ bb1,
                                                 const u16* __restrict__ B2h,
                                                 const float* __restrict__ b2,
                                                 const float* __restrict__ gn, const float* __restrict__ bn,
                                                 float* __restrict__ h, float* __restrict__ hnb,
                                                 u16* __restrict__ hb, int first) {
  __shared__ u16 Us[16][264];          // 16x256 U tile, row pad 8 u16 (2-way LDS aliasing = free)
  __shared__ float red[4][16][2];
  int tid = threadIdx.x;
  int wv = tid >> 6, lane = tid & 63;
  int c16 = lane & 15, kg = lane >> 4;
  int row0 = blockIdx.x * 16;          // NN % 16 == 0

  // ---- GEMM1 ----
  const u16* pAh = Ah + (size_t)(row0 + c16) * HH + kg * 8;
  const u16* pAl = Al + (size_t)(row0 + c16) * HH + kg * 8;
  bf16x8 ah[4], al[4];
  #pragma unroll
  for (int ks = 0; ks < 4; ++ks) {
    ah[ks] = *(const bf16x8*)(pAh + ks * 32);
    al[ks] = *(const bf16x8*)(pAl + ks * 32);
  }
  f32x4 acc[4];
  #pragma unroll
  for (int i = 0; i < 4; ++i) acc[i] = (f32x4){0.f, 0.f, 0.f, 0.f};
  #pragma unroll
  for (int ch = 0; ch < 4; ++ch) {     // B1 layout [ch4][tI16][lane][8]
    #pragma unroll
    for (int i = 0; i < 4; ++i) {
      int tI = wv * 4 + i;
      size_t boff = ((size_t)(ch * 16 + tI) * 64 + lane) * 8;
      bf16x8 bh = *(const bf16x8*)&B1h[boff];
      acc[i] = __builtin_amdgcn_mfma_f32_16x16x32_bf16(ah[ch], bh, acc[i], 0, 0, 0);
      acc[i] = __builtin_amdgcn_mfma_f32_16x16x32_bf16(al[ch], bh, acc[i], 0, 0, 0);
    }
  }
  {
    float bv[4], gv[4], bbv[4];
    #pragma unroll
    for (int i = 0; i < 4; ++i) {
      int c = (wv * 4 + i) * 16 + c16;
      bv[i] = b1[c]; gv[i] = g1[c]; bbv[i] = bb1[c];
    }
    float xv[4][4], s1[4], s2[4];
    #pragma unroll
    for (int j = 0; j < 4; ++j) {
      float a1 = 0.f, a2 = 0.f;
      #pragma unroll
      for (int i = 0; i < 4; ++i) {
        float v = acc[i][j] + bv[i];
        xv[j][i] = v; a1 += v; a2 = fmaf(v, v, a2);
      }
      #pragma unroll
      for (int m = 1; m <= 8; m <<= 1) { a1 += __shfl_xor(a1, m); a2 += __shfl_xor(a2, m); }
      s1[j] = a1; s2[j] = a2;
    }
    if (c16 == 0) {
      #pragma unroll
      for (int j = 0; j < 4; ++j) { red[wv][kg*4+j][0] = s1[j]; red[wv][kg*4+j][1] = s2[j]; }
    }
    __syncthreads();
    #pragma unroll
    for (int j = 0; j < 4; ++j) {
      int row = kg * 4 + j;
      float S1 = red[0][row][0] + red[1][row][0] + red[2][row][0] + red[3][row][0];
      float S2 = red[0][row][1] + red[1][row][1] + red[2][row][1] + red[3][row][1];
      float mu = S1 * (1.f / 256.f);
      float var = fmaxf(S2 * (1.f / 256.f) - mu * mu, 0.f);
      float rs = rsqrtf(var + LN_EPS_);
      #pragma unroll
      for (int i = 0; i < 4; ++i) {
        float o = fmaxf((xv[j][i] - mu) * rs * gv[i] + bbv[i], 0.f);
        Us[row][(wv * 4 + i) * 16 + c16] = bf16_rne(o);
      }
    }
  }
  __syncthreads();

  // ---- GEMM2 ----
  bf16x8 ua[8];
  #pragma unroll
  for (int ks = 0; ks < 8; ++ks) ua[ks] = *(const bf16x8*)&Us[c16][ks * 32 + kg * 8];
  f32x4 acc2[2];
  #pragma unroll
  for (int i = 0; i < 2; ++i) acc2[i] = (f32x4){0.f, 0.f, 0.f, 0.f};
  #pragma unroll
  for (int ch = 0; ch < 4; ++ch) {     // B2 layout [ch4][tI8][ks2(2)][lane][8]
    #pragma unroll
    for (int ks2 = 0; ks2 < 2; ++ks2) {
      int ks = ch * 2 + ks2;
      #pragma unroll
      for (int i = 0; i < 2; ++i) {
        int tI = wv * 2 + i;
        size_t boff = ((size_t)(ch * 16 + tI * 2 + ks2) * 64 + lane) * 8;
        bf16x8 bh = *(const bf16x8*)&B2h[boff];
        acc2[i] = __builtin_amdgcn_mfma_f32_16x16x32_bf16(ua[ks], bh, acc2[i], 0, 0, 0);
      }
    }
  }
  {
    float bv[2], gv[2], bnv[2];
    #pragma unroll
    for (int i = 0; i < 2; ++i) {
      int c = (wv * 2 + i) * 16 + c16;
      bv[i] = b2[c]; gv[i] = gn[c]; bnv[i] = bn[c];
    }
    float xv[4][2], s1[4], s2[4];
    #pragma unroll
    for (int j = 0; j < 4; ++j) {
      int row = row0 + kg * 4 + j;
      float a1 = 0.f, a2 = 0.f;
      #pragma unroll
      for (int i = 0; i < 2; ++i) {
        size_t p = (size_t)row * HH + (wv * 2 + i) * 16 + c16;
        float v = acc2[i][j] + bv[i];
        if (!first) v += h[p];
        xv[j][i] = v;
        h[p] = v;
        a1 += v; a2 = fmaf(v, v, a2);
      }
      #pragma unroll
      for (int m = 1; m <= 8; m <<= 1) { a1 += __shfl_xor(a1, m); a2 += __shfl_xor(a2, m); }
      s1[j] = a1; s2[j] = a2;
    }
    if (c16 == 0) {
      #pragma unroll
      for (int j = 0; j < 4; ++j) { red[wv][kg*4+j][0] = s1[j]; red[wv][kg*4+j][1] = s2[j]; }
    }
    __syncthreads();
    #pragma unroll
    for (int j = 0; j < 4; ++j) {
      int row = kg * 4 + j;
      float S1 = red[0][row][0] + red[1][row][0] + red[2][row][0] + red[3][row][0];
      float S2 = red[0][row][1] + red[1][row][1] + red[2][row][1] + red[3][row][1];
      float mu = S1 * (1.f / 128.f);
      float var = fmaxf(S2 * (1.f / 128.f) - mu * mu, 0.f);
      float rs = rsqrtf(var + LN_EPS_);
      #pragma unroll
      for (int i = 0; i < 2; ++i) {
        float o = fmaxf((xv[j][i] - mu) * rs * gv[i] + bnv[i], 0.f);
        size_t p = (size_t)(row0 + row) * HH + (wv * 2 + i) * 16 + c16;
        hnb[p] = o;
        hb[p] = bf16_rne(o);
      }
    }
  }
}

// ---------------- final output GEMM (Nx128 @ 128x16) ----------------
__global__ __launch_bounds__(256) void outgemm_kernel(const float* __restrict__ hn, const float* __restrict__ w,
                                                      const float* __restrict__ b, float* __restrict__ out) {
  __shared__ float Ws[HH * DOUT_];
  int tid = threadIdx.x;
  {
    const float4* s4 = (const float4*)w;
    float4* d4 = (float4*)Ws;
    d4[tid*2] = s4[tid*2]; d4[tid*2+1] = s4[tid*2+1];
  }
  __syncthreads();
  int id = blockIdx.x * 256 + tid;
  int n = id >> 4, c = id & 15;
  if (n >= NN) return;
  float s = b[c];
  const float* hr = &hn[(size_t)n*HH];
  #pragma unroll 8
  for (int k = 0; k < HH; ++k) s += hr[k] * Ws[k*DOUT_ + c];
  out[n*DOUT_ + c] = s;
}

extern "C" void kernel_launch(void* const* d_in, const int* in_sizes, int n_in,
                              void* d_out, int out_size, void* d_ws, size_t ws_size,
                              hipStream_t stream) {
  const float* x    = (const float*)d_in[0];
  const int*   ei   = (const int*)d_in[1];
  const float* eatt = (const float*)d_in[2];
  const float* enw  = (const float*)d_in[3];
  const float* enb  = (const float*)d_in[4];
  const float* eew  = (const float*)d_in[5];
  const float* eeb  = (const float*)d_in[6];
  const float* t    = (const float*)d_in[7];
  const float* m1w  = (const float*)d_in[8];
  const float* m1b  = (const float*)d_in[9];
  const float* mlg  = (const float*)d_in[10];
  const float* mlb  = (const float*)d_in[11];
  const float* m2w  = (const float*)d_in[12];
  const float* m2b  = (const float*)d_in[13];
  const float* lng  = (const float*)d_in[14];
  const float* lnb  = (const float*)d_in[15];
  const float* linw = (const float*)d_in[16];
  const float* linb = (const float*)d_in[17];
  float* out = (float*)d_out;

  char* ws = (char*)d_ws;
  size_t o = 0;
  auto take = [&](size_t bytes) { char* p = ws + o; o = (o + bytes + 255) & ~(size_t)255; return p; };
  int*    deg  = (int*)take((size_t)NN * 4);
  int*    off  = (int*)take((size_t)(NN + 1) * 4);
  int*    cur  = (int*)take((size_t)NN * 4);
  int*    srcs = (int*)take((size_t)EE * 4);
  float4* ea4  = (float4*)take((size_t)EE * 16);
  float*  h    = (float*)take((size_t)NN * HH * 4);
  float*  hnb  = (float*)take((size_t)NN * HH * 4);
  u16*    hb   = (u16*)take((size_t)NN * HH * 2);
  u16*    tmpH = (u16*)take((size_t)NN * HH * 2);
  u16*    tmpL = (u16*)take((size_t)NN * HH * 2);
  u16*    w1h  = (u16*)take((size_t)LL * HH * 256 * 2);
  u16*    w2h  = (u16*)take((size_t)LL * 256 * HH * 2);

  const int* src = ei;
  const int* dst = ei + EE;

  hipMemsetAsync(deg, 0, (size_t)NN * 4, stream);
  hist_kernel<<<(EE + 255) / 256, 256, 0, stream>>>(dst, deg);
  scan_kernel<<<1, 1024, 0, stream>>>(deg, off, cur);
  scatter_kernel<<<(EE + 255) / 256, 256, 0, stream>>>(src, dst, (const float4*)eatt, cur, srcs, ea4);
  int wblocks = (LL * HH * 256 / 8 + 255) / 256;   // 192
  wpack_kernel<<<wblocks, 256, 0, stream>>>(m1w, w1h, HH, 256, 1);   // [ch4][tI16][lane][8]
  wpack_kernel<<<wblocks, 256, 0, stream>>>(m2w, w2h, 256, HH, 2);   // [ch4][tI8][ks2][lane][8]
  encoder_kernel<<<(NN * 64 + 255) / 256, 256, 0, stream>>>(x, enw, enb, h, hb);

  int gblocks = NN / 16;   // 1250
  for (int i = 0; i < LL; ++i) {
    const float* cin = (i == 0) ? h : hnb;
    conv_kernel<<<(NN + 3) / 4, 256, 0, stream>>>(cin, hb, off, srcs, ea4, eew, eeb, t, i, tmpH, tmpL);
    int nrm = (i + 1) % LL;  // layer i's output normed with ln params of layer i+1 (layer 0 for final norm)
    mlp_fused<<<gblocks, 256, 0, stream>>>(tmpH, tmpL,
                                           w1h + (size_t)i * 32768,
                                           m1b + i * 256, mlg + i * 256, mlb + i * 256,
                                           w2h + (size_t)i * 32768,
                                           m2b + i * HH, lng + nrm * HH, lnb + nrm * HH,
                                           h, hnb, hb, i == 0 ? 1 : 0);
  }
  outgemm_kernel<<<(NN * DOUT_ + 255) / 256, 256, 0, stream>>>(hnb, linw, linb, out);
}

// Round 16
// 917.867 us; speedup vs baseline: 1.0749x; 1.0749x over previous
//
#include <hip/hip_runtime.h>
#include <hip/hip_bf16.h>
#include <math.h>

#define NN 20000
#define EE 640000
#define HH 128
#define LL 12
#define DOUT_ 16
#define EPS_ 1e-7f
#define LN_EPS_ 1e-5f

typedef unsigned short u16;
typedef unsigned int u32;
typedef __attribute__((ext_vector_type(8))) short bf16x8;
typedef __attribute__((ext_vector_type(4))) float f32x4;

__device__ inline u16 bf16_rne(float v) {
  u32 u = __float_as_uint(v);
  return (u16)((u + 0x7FFFu + ((u >> 16) & 1u)) >> 16);
}
__device__ inline float bf16_tof(u16 h) { return __uint_as_float(((u32)h) << 16); }

// ---------------- CSR build ----------------
__global__ __launch_bounds__(256) void hist_kernel(const int* __restrict__ dst, int* __restrict__ deg) {
  int e = blockIdx.x * 256 + threadIdx.x;
  if (e < EE) atomicAdd(&deg[dst[e]], 1);
}

__global__ __launch_bounds__(1024) void scan_kernel(const int* __restrict__ deg, int* __restrict__ off,
                                                    int* __restrict__ cur) {
  __shared__ int part[1024];
  int tid = threadIdx.x;
  const int CH = (NN + 1023) >> 10;   // 20
  int base = tid * CH;
  int s = 0;
  for (int j = 0; j < CH; ++j) { int i = base + j; if (i < NN) s += deg[i]; }
  part[tid] = s;
  __syncthreads();
  for (int d = 1; d < 1024; d <<= 1) {
    int v = (tid >= d) ? part[tid - d] : 0;
    __syncthreads();
    part[tid] += v;
    __syncthreads();
  }
  int run = part[tid] - s;  // exclusive prefix
  for (int j = 0; j < CH; ++j) {
    int i = base + j;
    if (i < NN) { off[i] = run; cur[i] = run; run += deg[i]; }
  }
  if (tid == 1023) off[NN] = part[1023];
}

__global__ __launch_bounds__(256) void scatter_kernel(const int* __restrict__ src, const int* __restrict__ dst,
                                                      const float4* __restrict__ ea, int* __restrict__ cur,
                                                      int* __restrict__ srcs, float4* __restrict__ ea4) {
  int e = blockIdx.x * 256 + threadIdx.x;
  if (e >= EE) return;
  int d = dst[e];
  int p = atomicAdd(&cur[d], 1);
  srcs[p] = src[e];
  ea4[p] = ea[e];
}

// ---------------- degree-sorted node order (descending) for conv load balance ----------------
__global__ __launch_bounds__(256) void degbin_kernel(const int* __restrict__ deg, int* __restrict__ bh) {
  int n = blockIdx.x * 256 + threadIdx.x;
  if (n >= NN) return;
  int d = deg[n]; if (d > 127) d = 127;
  atomicAdd(&bh[d], 1);
}

// descending-degree exclusive prefix: pos[b] = sum of counts of bins > b
__global__ __launch_bounds__(128) void degscan_kernel(const int* __restrict__ bh, int* __restrict__ bcur) {
  __shared__ int c[128];
  int t = threadIdx.x;
  c[t] = bh[t];
  __syncthreads();
  int pos = 0;
  for (int b = t + 1; b < 128; ++b) pos += c[b];   // 128 iters, trivial cost
  bcur[t] = pos;
}

__global__ __launch_bounds__(256) void degscatter_kernel(const int* __restrict__ deg, int* __restrict__ bcur,
                                                         int* __restrict__ order) {
  int n = blockIdx.x * 256 + threadIdx.x;
  if (n >= NN) return;
  int d = deg[n]; if (d > 127) d = 127;
  int p = atomicAdd(&bcur[d], 1);
  order[p] = n;
}

// ---------------- weight pack: fp32 [L][K][N] -> bf16 (hi only) MFMA-fragment order ----------------
// layout: [l][chunk][tI(N/16)][ks2(KSC)][lane(64)][j(8)]; k = (chunk*KSC+ks2)*32 + (lane>>4)*8 + j
__global__ __launch_bounds__(256) void wpack_kernel(const float* __restrict__ w, u16* __restrict__ dh,
                                                    int K, int N, int KSC) {
  int fid = blockIdx.x * 256 + threadIdx.x;
  int perL = (K * N) >> 3;
  if (fid >= LL * perL) return;
  int l = fid / perL, r = fid % perL;
  int lane = r & 63;
  int r2 = r >> 6;
  int ks2 = r2 % KSC; r2 /= KSC;
  int NT = N >> 4;
  int tI = r2 % NT;
  int chunk = r2 / NT;
  int c16 = lane & 15, kg = lane >> 4;
  int n = tI * 16 + c16;
  int k0 = (chunk * KSC + ks2) * 32 + kg * 8;
  const float* ws = w + (size_t)l * K * N;
  u16* oh = dh + (size_t)fid * 8;
  #pragma unroll
  for (int j = 0; j < 8; ++j) {
    oh[j] = bf16_rne(ws[(size_t)(k0 + j) * N + n]);
  }
}

// ---------------- encoder: h fp32 + hb bf16 plane ----------------
__global__ __launch_bounds__(256) void encoder_kernel(const float* __restrict__ x, const float* __restrict__ w,
                                                      const float* __restrict__ b, float* __restrict__ h,
                                                      u16* __restrict__ hb) {
  int id = blockIdx.x * 256 + threadIdx.x;
  if (id >= NN * 64) return;
  int n = id >> 6, cp = id & 63;
  int c0 = cp * 2;
  float x0 = x[n*3+0], x1 = x[n*3+1], x2 = x[n*3+2];
  float vx = b[c0]   + x0*w[c0]   + x1*w[HH+c0]   + x2*w[2*HH+c0];
  float vy = b[c0+1] + x0*w[c0+1] + x1*w[HH+c0+1] + x2*w[2*HH+c0+1];
  *(float2*)&h[(size_t)n*HH + c0] = make_float2(vx, vy);
  *(u32*)&hb[(size_t)n*HH + c0] = (u32)bf16_rne(vx) | ((u32)bf16_rne(vy) << 16);
}

// ---------------- GENConv aggregation: wave per dst node (round-12 proven body) ----------------
// Node assignment via degree-sorted order[] (descending): blocks contain equal-degree
// nodes -> block runtime ~ mean not max; grid drains with the smallest nodes.
__global__ __launch_bounds__(256) void conv_kernel(const float* __restrict__ hn,
                                                   const u16* __restrict__ hb,
                                                   const int* __restrict__ off,
                                                   const int* __restrict__ order,
                                                   const int* __restrict__ srcs, const float4* __restrict__ ea4,
                                                   const float* __restrict__ eew, const float* __restrict__ eeb,
                                                   const float* __restrict__ t, int layer,
                                                   u16* __restrict__ tmpH, u16* __restrict__ tmpL) {
  int slot = blockIdx.x * 4 + (threadIdx.x >> 6);
  int lane = threadIdx.x & 63;
  if (slot >= NN) return;
  int wid = order[slot];
  int c0 = lane * 2;
  float ti = t[layer];
  float w0x = eew[c0],      w0y = eew[c0+1];
  float w1x = eew[HH+c0],   w1y = eew[HH+c0+1];
  float w2x = eew[2*HH+c0], w2y = eew[2*HH+c0+1];
  float w3x = eew[3*HH+c0], w3y = eew[3*HH+c0+1];
  float bx = eeb[c0], by = eeb[c0+1];
  int e0 = off[wid], e1 = off[wid+1];
  float2 hd = *(const float2*)&hn[(size_t)wid*HH + c0];
  float den0 = 0.f, den1 = 0.f, num0 = 0.f, num1 = 0.f;

  int e = e0;
  const int UF = 8;
  for (; e + UF <= e1; e += UF) {
    int si[UF]; float4 av[UF];
    #pragma unroll
    for (int u = 0; u < UF; ++u) { si[u] = srcs[e + u]; av[u] = ea4[e + u]; }
    u32 hv[UF];
    #pragma unroll
    for (int u = 0; u < UF; ++u) hv[u] = *(const u32*)&hb[((u32)si[u] << 7) + c0];
    #pragma unroll
    for (int u = 0; u < UF; ++u) {
      float hx = bf16_tof((u16)(hv[u] & 0xffffu));
      float hy = bf16_tof((u16)(hv[u] >> 16));
      float eax = fmaf(av[u].w, w3x, fmaf(av[u].z, w2x, fmaf(av[u].y, w1x, fmaf(av[u].x, w0x, bx))));
      float eay = fmaf(av[u].w, w3y, fmaf(av[u].z, w2y, fmaf(av[u].y, w1y, fmaf(av[u].x, w0y, by))));
      float m0 = fmaxf(hx + eax, 0.f) + EPS_;
      float m1 = fmaxf(hy + eay, 0.f) + EPS_;
      float p0 = __expf(m0 * ti);
      float p1 = __expf(m1 * ti);
      den0 += p0; den1 += p1;
      num0 = fmaf(m0, p0, num0);
      num1 = fmaf(m1, p1, num1);
    }
  }
  for (; e < e1; ++e) {
    int sidx = srcs[e];
    float4 a = ea4[e];
    u32 hv = *(const u32*)&hb[((u32)sidx << 7) + c0];
    float hx = bf16_tof((u16)(hv & 0xffffu));
    float hy = bf16_tof((u16)(hv >> 16));
    float eax = fmaf(a.w, w3x, fmaf(a.z, w2x, fmaf(a.y, w1x, fmaf(a.x, w0x, bx))));
    float eay = fmaf(a.w, w3y, fmaf(a.z, w2y, fmaf(a.y, w1y, fmaf(a.x, w0y, by))));
    float m0 = fmaxf(hx + eax, 0.f) + EPS_;
    float m1 = fmaxf(hy + eay, 0.f) + EPS_;
    float p0 = __expf(m0 * ti);
    float p1 = __expf(m1 * ti);
    den0 += p0; den1 += p1;
    num0 = fmaf(m0, p0, num0);
    num1 = fmaf(m1, p1, num1);
  }
  float v0 = num0 / (den0 + 1e-16f) + hd.x;
  float v1 = num1 / (den1 + 1e-16f) + hd.y;
  u16 h0 = bf16_rne(v0), h1 = bf16_rne(v1);
  u16 l0 = bf16_rne(v0 - bf16_tof(h0)), l1 = bf16_rne(v1 - bf16_tof(h1));
  *(u32*)&tmpH[(size_t)wid*HH + c0] = (u32)h0 | ((u32)h1 << 16);
  *(u32*)&tmpL[(size_t)wid*HH + c0] = (u32)l0 | ((u32)l1 << 16);
}

// ---------------- fused MLP: GEMM1 + LN(256) + ReLU -> LDS -> GEMM2 + residual + LN(128) ----------------
__global__ __launch_bounds__(256) void mlp_fused(const u16* __restrict__ Ah, const u16* __restrict__ Al,
                                                 const u16* __restrict__ B1h,
                                                 const float* __restrict__ b1,
                                                 const float* __restrict__ g1, const float* __restrict__ bb1,
                                                 const u16* __restrict__ B2h,
                                                 const float* __restrict__ b2,
                                                 const float* __restrict__ gn, const float* __restrict__ bn,
                                                 float* __restrict__ h, float* __restrict__ hnb,
                                                 u16* __restrict__ hb, int first) {
  __shared__ u16 Us[16][264];          // 16x256 U tile, row pad 8 u16
  __shared__ float red[4][16][2];
  int tid = threadIdx.x;
  int wv = tid >> 6, lane = tid & 63;
  int c16 = lane & 15, kg = lane >> 4;
  int row0 = blockIdx.x * 16;          // NN % 16 == 0

  // ---- GEMM1 ----
  const u16* pAh = Ah + (size_t)(row0 + c16) * HH + kg * 8;
  const u16* pAl = Al + (size_t)(row0 + c16) * HH + kg * 8;
  bf16x8 ah[4], al[4];
  #pragma unroll
  for (int ks = 0; ks < 4; ++ks) {
    ah[ks] = *(const bf16x8*)(pAh + ks * 32);
    al[ks] = *(const bf16x8*)(pAl + ks * 32);
  }
  f32x4 acc[4];
  #pragma unroll
  for (int i = 0; i < 4; ++i) acc[i] = (f32x4){0.f, 0.f, 0.f, 0.f};
  #pragma unroll
  for (int ch = 0; ch < 4; ++ch) {     // B1 layout [ch4][tI16][lane][8]
    #pragma unroll
    for (int i = 0; i < 4; ++i) {
      int tI = wv * 4 + i;
      size_t boff = ((size_t)(ch * 16 + tI) * 64 + lane) * 8;
      bf16x8 bh = *(const bf16x8*)&B1h[boff];
      acc[i] = __builtin_amdgcn_mfma_f32_16x16x32_bf16(ah[ch], bh, acc[i], 0, 0, 0);
      acc[i] = __builtin_amdgcn_mfma_f32_16x16x32_bf16(al[ch], bh, acc[i], 0, 0, 0);
    }
  }
  {
    float bv[4], gv[4], bbv[4];
    #pragma unroll
    for (int i = 0; i < 4; ++i) {
      int c = (wv * 4 + i) * 16 + c16;
      bv[i] = b1[c]; gv[i] = g1[c]; bbv[i] = bb1[c];
    }
    float xv[4][4], s1[4], s2[4];
    #pragma unroll
    for (int j = 0; j < 4; ++j) {
      float a1 = 0.f, a2 = 0.f;
      #pragma unroll
      for (int i = 0; i < 4; ++i) {
        float v = acc[i][j] + bv[i];
        xv[j][i] = v; a1 += v; a2 = fmaf(v, v, a2);
      }
      #pragma unroll
      for (int m = 1; m <= 8; m <<= 1) { a1 += __shfl_xor(a1, m); a2 += __shfl_xor(a2, m); }
      s1[j] = a1; s2[j] = a2;
    }
    if (c16 == 0) {
      #pragma unroll
      for (int j = 0; j < 4; ++j) { red[wv][kg*4+j][0] = s1[j]; red[wv][kg*4+j][1] = s2[j]; }
    }
    __syncthreads();
    #pragma unroll
    for (int j = 0; j < 4; ++j) {
      int row = kg * 4 + j;
      float S1 = red[0][row][0] + red[1][row][0] + red[2][row][0] + red[3][row][0];
      float S2 = red[0][row][1] + red[1][row][1] + red[2][row][1] + red[3][row][1];
      float mu = S1 * (1.f / 256.f);
      float var = fmaxf(S2 * (1.f / 256.f) - mu * mu, 0.f);
      float rs = rsqrtf(var + LN_EPS_);
      #pragma unroll
      for (int i = 0; i < 4; ++i) {
        float o = fmaxf((xv[j][i] - mu) * rs * gv[i] + bbv[i], 0.f);
        Us[row][(wv * 4 + i) * 16 + c16] = bf16_rne(o);
      }
    }
  }
  __syncthreads();

  // ---- GEMM2 ----
  bf16x8 ua[8];
  #pragma unroll
  for (int ks = 0; ks < 8; ++ks) ua[ks] = *(const bf16x8*)&Us[c16][ks * 32 + kg * 8];
  f32x4 acc2[2];
  #pragma unroll
  for (int i = 0; i < 2; ++i) acc2[i] = (f32x4){0.f, 0.f, 0.f, 0.f};
  #pragma unroll
  for (int ch = 0; ch < 4; ++ch) {     // B2 layout [ch4][tI8][ks2(2)][lane][8]
    #pragma unroll
    for (int ks2 = 0; ks2 < 2; ++ks2) {
      int ks = ch * 2 + ks2;
      #pragma unroll
      for (int i = 0; i < 2; ++i) {
        int tI = wv * 2 + i;
        size_t boff = ((size_t)(ch * 16 + tI * 2 + ks2) * 64 + lane) * 8;
        bf16x8 bh = *(const bf16x8*)&B2h[boff];
        acc2[i] = __builtin_amdgcn_mfma_f32_16x16x32_bf16(ua[ks], bh, acc2[i], 0, 0, 0);
      }
    }
  }
  {
    float bv[2], gv[2], bnv[2];
    #pragma unroll
    for (int i = 0; i < 2; ++i) {
      int c = (wv * 2 + i) * 16 + c16;
      bv[i] = b2[c]; gv[i] = gn[c]; bnv[i] = bn[c];
    }
    float xv[4][2], s1[4], s2[4];
    #pragma unroll
    for (int j = 0; j < 4; ++j) {
      int row = row0 + kg * 4 + j;
      float a1 = 0.f, a2 = 0.f;
      #pragma unroll
      for (int i = 0; i < 2; ++i) {
        size_t p = (size_t)row * HH + (wv * 2 + i) * 16 + c16;
        float v = acc2[i][j] + bv[i];
        if (!first) v += h[p];
        xv[j][i] = v;
        h[p] = v;
        a1 += v; a2 = fmaf(v, v, a2);
      }
      #pragma unroll
      for (int m = 1; m <= 8; m <<= 1) { a1 += __shfl_xor(a1, m); a2 += __shfl_xor(a2, m); }
      s1[j] = a1; s2[j] = a2;
    }
    if (c16 == 0) {
      #pragma unroll
      for (int j = 0; j < 4; ++j) { red[wv][kg*4+j][0] = s1[j]; red[wv][kg*4+j][1] = s2[j]; }
    }
    __syncthreads();
    #pragma unroll
    for (int j = 0; j < 4; ++j) {
      int row = kg * 4 + j;
      float S1 = red[0][row][0] + red[1][row][0] + red[2][row][0] + red[3][row][0];
      float S2 = red[0][row][1] + red[1][row][1] + red[2][row][1] + red[3][row][1];
      float mu = S1 * (1.f / 128.f);
      float var = fmaxf(S2 * (1.f / 128.f) - mu * mu, 0.f);
      float rs = rsqrtf(var + LN_EPS_);
      #pragma unroll
      for (int i = 0; i < 2; ++i) {
        float o = fmaxf((xv[j][i] - mu) * rs * gv[i] + bnv[i], 0.f);
        size_t p = (size_t)(row0 + row) * HH + (wv * 2 + i) * 16 + c16;
        hnb[p] = o;
        hb[p] = bf16_rne(o);
      }
    }
  }
}

// ---------------- final output GEMM (Nx128 @ 128x16) ----------------
__global__ __launch_bounds__(256) void outgemm_kernel(const float* __restrict__ hn, const float* __restrict__ w,
                                                      const float* __restrict__ b, float* __restrict__ out) {
  __shared__ float Ws[HH * DOUT_];
  int tid = threadIdx.x;
  {
    const float4* s4 = (const float4*)w;
    float4* d4 = (float4*)Ws;
    d4[tid*2] = s4[tid*2]; d4[tid*2+1] = s4[tid*2+1];
  }
  __syncthreads();
  int id = blockIdx.x * 256 + tid;
  int n = id >> 4, c = id & 15;
  if (n >= NN) return;
  float s = b[c];
  const float* hr = &hn[(size_t)n*HH];
  #pragma unroll 8
  for (int k = 0; k < HH; ++k) s += hr[k] * Ws[k*DOUT_ + c];
  out[n*DOUT_ + c] = s;
}

extern "C" void kernel_launch(void* const* d_in, const int* in_sizes, int n_in,
                              void* d_out, int out_size, void* d_ws, size_t ws_size,
                              hipStream_t stream) {
  const float* x    = (const float*)d_in[0];
  const int*   ei   = (const int*)d_in[1];
  const float* eatt = (const float*)d_in[2];
  const float* enw  = (const float*)d_in[3];
  const float* enb  = (const float*)d_in[4];
  const float* eew  = (const float*)d_in[5];
  const float* eeb  = (const float*)d_in[6];
  const float* t    = (const float*)d_in[7];
  const float* m1w  = (const float*)d_in[8];
  const float* m1b  = (const float*)d_in[9];
  const float* mlg  = (const float*)d_in[10];
  const float* mlb  = (const float*)d_in[11];
  const float* m2w  = (const float*)d_in[12];
  const float* m2b  = (const float*)d_in[13];
  const float* lng  = (const float*)d_in[14];
  const float* lnb  = (const float*)d_in[15];
  const float* linw = (const float*)d_in[16];
  const float* linb = (const float*)d_in[17];
  float* out = (float*)d_out;

  char* ws = (char*)d_ws;
  size_t o = 0;
  auto take = [&](size_t bytes) { char* p = ws + o; o = (o + bytes + 255) & ~(size_t)255; return p; };
  int*    deg   = (int*)take((size_t)NN * 4);
  int*    off   = (int*)take((size_t)(NN + 1) * 4);
  int*    cur   = (int*)take((size_t)NN * 4);
  int*    srcs  = (int*)take((size_t)EE * 4);
  float4* ea4   = (float4*)take((size_t)EE * 16);
  int*    bh    = (int*)take(128 * 4);
  int*    bcur  = (int*)take(128 * 4);
  int*    order = (int*)take((size_t)NN * 4);
  float*  h     = (float*)take((size_t)NN * HH * 4);
  float*  hnb   = (float*)take((size_t)NN * HH * 4);
  u16*    hb    = (u16*)take((size_t)NN * HH * 2);
  u16*    tmpH  = (u16*)take((size_t)NN * HH * 2);
  u16*    tmpL  = (u16*)take((size_t)NN * HH * 2);
  u16*    w1h   = (u16*)take((size_t)LL * HH * 256 * 2);
  u16*    w2h   = (u16*)take((size_t)LL * 256 * HH * 2);

  const int* src = ei;
  const int* dst = ei + EE;

  hipMemsetAsync(deg, 0, (size_t)NN * 4, stream);
  hipMemsetAsync(bh, 0, 128 * 4, stream);
  hist_kernel<<<(EE + 255) / 256, 256, 0, stream>>>(dst, deg);
  scan_kernel<<<1, 1024, 0, stream>>>(deg, off, cur);
  scatter_kernel<<<(EE + 255) / 256, 256, 0, stream>>>(src, dst, (const float4*)eatt, cur, srcs, ea4);
  // degree-sorted node order (descending) for conv
  degbin_kernel<<<(NN + 255) / 256, 256, 0, stream>>>(deg, bh);
  degscan_kernel<<<1, 128, 0, stream>>>(bh, bcur);
  degscatter_kernel<<<(NN + 255) / 256, 256, 0, stream>>>(deg, bcur, order);

  int wblocks = (LL * HH * 256 / 8 + 255) / 256;   // 192
  wpack_kernel<<<wblocks, 256, 0, stream>>>(m1w, w1h, HH, 256, 1);   // [ch4][tI16][lane][8]
  wpack_kernel<<<wblocks, 256, 0, stream>>>(m2w, w2h, 256, HH, 2);   // [ch4][tI8][ks2][lane][8]
  encoder_kernel<<<(NN * 64 + 255) / 256, 256, 0, stream>>>(x, enw, enb, h, hb);

  int gblocks = NN / 16;   // 1250
  for (int i = 0; i < LL; ++i) {
    const float* cin = (i == 0) ? h : hnb;
    conv_kernel<<<(NN + 3) / 4, 256, 0, stream>>>(cin, hb, off, order, srcs, ea4, eew, eeb, t, i, tmpH, tmpL);
    int nrm = (i + 1) % LL;  // layer i's output normed with ln params of layer i+1 (layer 0 for final norm)
    mlp_fused<<<gblocks, 256, 0, stream>>>(tmpH, tmpL,
                                           w1h + (size_t)i * 32768,
                                           m1b + i * 256, mlg + i * 256, mlb + i * 256,
                                           w2h + (size_t)i * 32768,
                                           m2b + i * HH, lng + nrm * HH, lnb + nrm * HH,
                                           h, hnb, hb, i == 0 ? 1 : 0);
  }
  outgemm_kernel<<<(NN * DOUT_ + 255) / 256, 256, 0, stream>>>(hnb, linw, linb, out);
}

// Round 17
// 886.403 us; speedup vs baseline: 1.1131x; 1.0355x over previous
//
#include <hip/hip_runtime.h>
#include <hip/hip_bf16.h>
#include <math.h>

#define NN 20000
#define EE 640000
#define HH 128
#define LL 12
#define DOUT_ 16
#define EPS_ 1e-7f
#define LN_EPS_ 1e-5f

typedef unsigned short u16;
typedef unsigned int u32;
typedef __attribute__((ext_vector_type(8))) short bf16x8;
typedef __attribute__((ext_vector_type(4))) float f32x4;

__device__ inline u16 bf16_rne(float v) {
  u32 u = __float_as_uint(v);
  return (u16)((u + 0x7FFFu + ((u >> 16) & 1u)) >> 16);
}
__device__ inline float bf16_tof(u16 h) { return __uint_as_float(((u32)h) << 16); }

// ---------------- CSR build ----------------
__global__ __launch_bounds__(256) void hist_kernel(const int* __restrict__ dst, int* __restrict__ deg) {
  int e = blockIdx.x * 256 + threadIdx.x;
  if (e < EE) atomicAdd(&deg[dst[e]], 1);
}

__global__ __launch_bounds__(1024) void scan_kernel(const int* __restrict__ deg, int* __restrict__ off,
                                                    int* __restrict__ cur) {
  __shared__ int part[1024];
  int tid = threadIdx.x;
  const int CH = (NN + 1023) >> 10;   // 20
  int base = tid * CH;
  int s = 0;
  for (int j = 0; j < CH; ++j) { int i = base + j; if (i < NN) s += deg[i]; }
  part[tid] = s;
  __syncthreads();
  for (int d = 1; d < 1024; d <<= 1) {
    int v = (tid >= d) ? part[tid - d] : 0;
    __syncthreads();
    part[tid] += v;
    __syncthreads();
  }
  int run = part[tid] - s;  // exclusive prefix
  for (int j = 0; j < CH; ++j) {
    int i = base + j;
    if (i < NN) { off[i] = run; cur[i] = run; run += deg[i]; }
  }
  if (tid == 1023) off[NN] = part[1023];
}

__global__ __launch_bounds__(256) void scatter_kernel(const int* __restrict__ src, const int* __restrict__ dst,
                                                      const float4* __restrict__ ea, int* __restrict__ cur,
                                                      int* __restrict__ srcs, float4* __restrict__ ea4) {
  int e = blockIdx.x * 256 + threadIdx.x;
  if (e >= EE) return;
  int d = dst[e];
  int p = atomicAdd(&cur[d], 1);
  srcs[p] = src[e];
  ea4[p] = ea[e];
}

// ---------------- weight pack: fp32 [L][K][N] -> bf16 (hi only) MFMA-fragment order ----------------
// layout: [l][chunk][tI(N/16)][ks2(KSC)][lane(64)][j(8)]; k = (chunk*KSC+ks2)*32 + (lane>>4)*8 + j
__global__ __launch_bounds__(256) void wpack_kernel(const float* __restrict__ w, u16* __restrict__ dh,
                                                    int K, int N, int KSC) {
  int fid = blockIdx.x * 256 + threadIdx.x;
  int perL = (K * N) >> 3;
  if (fid >= LL * perL) return;
  int l = fid / perL, r = fid % perL;
  int lane = r & 63;
  int r2 = r >> 6;
  int ks2 = r2 % KSC; r2 /= KSC;
  int NT = N >> 4;
  int tI = r2 % NT;
  int chunk = r2 / NT;
  int c16 = lane & 15, kg = lane >> 4;
  int n = tI * 16 + c16;
  int k0 = (chunk * KSC + ks2) * 32 + kg * 8;
  const float* ws = w + (size_t)l * K * N;
  u16* oh = dh + (size_t)fid * 8;
  #pragma unroll
  for (int j = 0; j < 8; ++j) {
    oh[j] = bf16_rne(ws[(size_t)(k0 + j) * N + n]);
  }
}

// ---------------- encoder: h fp32 + hb bf16 plane ----------------
__global__ __launch_bounds__(256) void encoder_kernel(const float* __restrict__ x, const float* __restrict__ w,
                                                      const float* __restrict__ b, float* __restrict__ h,
                                                      u16* __restrict__ hb) {
  int id = blockIdx.x * 256 + threadIdx.x;
  if (id >= NN * 64) return;
  int n = id >> 6, cp = id & 63;
  int c0 = cp * 2;
  float x0 = x[n*3+0], x1 = x[n*3+1], x2 = x[n*3+2];
  float vx = b[c0]   + x0*w[c0]   + x1*w[HH+c0]   + x2*w[2*HH+c0];
  float vy = b[c0+1] + x0*w[c0+1] + x1*w[HH+c0+1] + x2*w[2*HH+c0+1];
  *(float2*)&h[(size_t)n*HH + c0] = make_float2(vx, vy);
  *(u32*)&hb[(size_t)n*HH + c0] = (u32)bf16_rne(vx) | ((u32)bf16_rne(vy) << 16);
}

// ---------------- GENConv aggregation: wave per dst node (round-12 proven form, verbatim) ----------------
__global__ __launch_bounds__(256) void conv_kernel(const float* __restrict__ hn,
                                                   const u16* __restrict__ hb,
                                                   const int* __restrict__ off,
                                                   const int* __restrict__ srcs, const float4* __restrict__ ea4,
                                                   const float* __restrict__ eew, const float* __restrict__ eeb,
                                                   const float* __restrict__ t, int layer,
                                                   u16* __restrict__ tmpH, u16* __restrict__ tmpL) {
  int wid = blockIdx.x * 4 + (threadIdx.x >> 6);
  int lane = threadIdx.x & 63;
  if (wid >= NN) return;
  int c0 = lane * 2;
  float ti = t[layer];
  float w0x = eew[c0],      w0y = eew[c0+1];
  float w1x = eew[HH+c0],   w1y = eew[HH+c0+1];
  float w2x = eew[2*HH+c0], w2y = eew[2*HH+c0+1];
  float w3x = eew[3*HH+c0], w3y = eew[3*HH+c0+1];
  float bx = eeb[c0], by = eeb[c0+1];
  int e0 = off[wid], e1 = off[wid+1];
  float2 hd = *(const float2*)&hn[(size_t)wid*HH + c0];
  float den0 = 0.f, den1 = 0.f, num0 = 0.f, num1 = 0.f;

  int e = e0;
  const int UF = 8;
  for (; e + UF <= e1; e += UF) {
    int si[UF]; float4 av[UF];
    #pragma unroll
    for (int u = 0; u < UF; ++u) { si[u] = srcs[e + u]; av[u] = ea4[e + u]; }
    u32 hv[UF];
    #pragma unroll
    for (int u = 0; u < UF; ++u) hv[u] = *(const u32*)&hb[((u32)si[u] << 7) + c0];
    #pragma unroll
    for (int u = 0; u < UF; ++u) {
      float hx = bf16_tof((u16)(hv[u] & 0xffffu));
      float hy = bf16_tof((u16)(hv[u] >> 16));
      float eax = fmaf(av[u].w, w3x, fmaf(av[u].z, w2x, fmaf(av[u].y, w1x, fmaf(av[u].x, w0x, bx))));
      float eay = fmaf(av[u].w, w3y, fmaf(av[u].z, w2y, fmaf(av[u].y, w1y, fmaf(av[u].x, w0y, by))));
      float m0 = fmaxf(hx + eax, 0.f) + EPS_;
      float m1 = fmaxf(hy + eay, 0.f) + EPS_;
      float p0 = __expf(m0 * ti);
      float p1 = __expf(m1 * ti);
      den0 += p0; den1 += p1;
      num0 = fmaf(m0, p0, num0);
      num1 = fmaf(m1, p1, num1);
    }
  }
  for (; e < e1; ++e) {
    int sidx = srcs[e];
    float4 a = ea4[e];
    u32 hv = *(const u32*)&hb[((u32)sidx << 7) + c0];
    float hx = bf16_tof((u16)(hv & 0xffffu));
    float hy = bf16_tof((u16)(hv >> 16));
    float eax = fmaf(a.w, w3x, fmaf(a.z, w2x, fmaf(a.y, w1x, fmaf(a.x, w0x, bx))));
    float eay = fmaf(a.w, w3y, fmaf(a.z, w2y, fmaf(a.y, w1y, fmaf(a.x, w0y, by))));
    float m0 = fmaxf(hx + eax, 0.f) + EPS_;
    float m1 = fmaxf(hy + eay, 0.f) + EPS_;
    float p0 = __expf(m0 * ti);
    float p1 = __expf(m1 * ti);
    den0 += p0; den1 += p1;
    num0 = fmaf(m0, p0, num0);
    num1 = fmaf(m1, p1, num1);
  }
  float v0 = num0 / (den0 + 1e-16f) + hd.x;
  float v1 = num1 / (den1 + 1e-16f) + hd.y;
  u16 h0 = bf16_rne(v0), h1 = bf16_rne(v1);
  u16 l0 = bf16_rne(v0 - bf16_tof(h0)), l1 = bf16_rne(v1 - bf16_tof(h1));
  *(u32*)&tmpH[(size_t)wid*HH + c0] = (u32)h0 | ((u32)h1 << 16);
  *(u32*)&tmpL[(size_t)wid*HH + c0] = (u32)l0 | ((u32)l1 << 16);
}

// ---------------- fused MLP, 32-row blocks: GEMM1+LN+ReLU -> LDS -> GEMM2+residual+LN ----------------
// block = 32 rows (2 row-tiles), 4 waves split N. Each B fragment is loaded ONCE
// and used by both row-tiles -> weight L2 traffic halves vs 16-row blocks.
// Per-row arithmetic identical to the 16-row version (same K-order, same LN).
__global__ __launch_bounds__(256) void mlp_fused(const u16* __restrict__ Ah, const u16* __restrict__ Al,
                                                 const u16* __restrict__ B1h,
                                                 const float* __restrict__ b1,
                                                 const float* __restrict__ g1, const float* __restrict__ bb1,
                                                 const u16* __restrict__ B2h,
                                                 const float* __restrict__ b2,
                                                 const float* __restrict__ gn, const float* __restrict__ bn,
                                                 float* __restrict__ h, float* __restrict__ hnb,
                                                 u16* __restrict__ hb, int first) {
  __shared__ u16 Us[32][264];          // 32x256 U tile, row pad 8 u16
  __shared__ float red[4][32][2];
  int tid = threadIdx.x;
  int wv = tid >> 6, lane = tid & 63;
  int c16 = lane & 15, kg = lane >> 4;
  int row0 = blockIdx.x * 32;          // NN % 32 == 0 (20000 = 625*32)

  // ---- GEMM1 ----
  f32x4 acc[2][4];
  #pragma unroll
  for (int rt = 0; rt < 2; ++rt)
    #pragma unroll
    for (int i = 0; i < 4; ++i) acc[rt][i] = (f32x4){0.f, 0.f, 0.f, 0.f};
  #pragma unroll
  for (int ch = 0; ch < 4; ++ch) {     // B1 layout [ch4][tI16][lane][8]
    bf16x8 a0h = *(const bf16x8*)(Ah + (size_t)(row0 + c16) * HH + ch * 32 + kg * 8);
    bf16x8 a0l = *(const bf16x8*)(Al + (size_t)(row0 + c16) * HH + ch * 32 + kg * 8);
    bf16x8 a1h = *(const bf16x8*)(Ah + (size_t)(row0 + 16 + c16) * HH + ch * 32 + kg * 8);
    bf16x8 a1l = *(const bf16x8*)(Al + (size_t)(row0 + 16 + c16) * HH + ch * 32 + kg * 8);
    #pragma unroll
    for (int i = 0; i < 4; ++i) {
      int tI = wv * 4 + i;
      size_t boff = ((size_t)(ch * 16 + tI) * 64 + lane) * 8;
      bf16x8 bh = *(const bf16x8*)&B1h[boff];
      acc[0][i] = __builtin_amdgcn_mfma_f32_16x16x32_bf16(a0h, bh, acc[0][i], 0, 0, 0);
      acc[0][i] = __builtin_amdgcn_mfma_f32_16x16x32_bf16(a0l, bh, acc[0][i], 0, 0, 0);
      acc[1][i] = __builtin_amdgcn_mfma_f32_16x16x32_bf16(a1h, bh, acc[1][i], 0, 0, 0);
      acc[1][i] = __builtin_amdgcn_mfma_f32_16x16x32_bf16(a1l, bh, acc[1][i], 0, 0, 0);
    }
  }
  {
    float bv[4], gv[4], bbv[4];
    #pragma unroll
    for (int i = 0; i < 4; ++i) {
      int c = (wv * 4 + i) * 16 + c16;
      bv[i] = b1[c]; gv[i] = g1[c]; bbv[i] = bb1[c];
    }
    float xv[2][4][4];
    #pragma unroll
    for (int rt = 0; rt < 2; ++rt) {
      #pragma unroll
      for (int j = 0; j < 4; ++j) {
        float a1 = 0.f, a2 = 0.f;
        #pragma unroll
        for (int i = 0; i < 4; ++i) {
          float v = acc[rt][i][j] + bv[i];
          xv[rt][j][i] = v; a1 += v; a2 = fmaf(v, v, a2);
        }
        #pragma unroll
        for (int m = 1; m <= 8; m <<= 1) { a1 += __shfl_xor(a1, m); a2 += __shfl_xor(a2, m); }
        if (c16 == 0) { red[wv][rt*16 + kg*4 + j][0] = a1; red[wv][rt*16 + kg*4 + j][1] = a2; }
      }
    }
    __syncthreads();
    #pragma unroll
    for (int rt = 0; rt < 2; ++rt) {
      #pragma unroll
      for (int j = 0; j < 4; ++j) {
        int row = rt * 16 + kg * 4 + j;
        float S1 = red[0][row][0] + red[1][row][0] + red[2][row][0] + red[3][row][0];
        float S2 = red[0][row][1] + red[1][row][1] + red[2][row][1] + red[3][row][1];
        float mu = S1 * (1.f / 256.f);
        float var = fmaxf(S2 * (1.f / 256.f) - mu * mu, 0.f);
        float rs = rsqrtf(var + LN_EPS_);
        #pragma unroll
        for (int i = 0; i < 4; ++i) {
          float o = fmaxf((xv[rt][j][i] - mu) * rs * gv[i] + bbv[i], 0.f);
          Us[row][(wv * 4 + i) * 16 + c16] = bf16_rne(o);
        }
      }
    }
  }
  __syncthreads();

  // ---- GEMM2 ----
  f32x4 acc2[2][2];
  #pragma unroll
  for (int rt = 0; rt < 2; ++rt)
    #pragma unroll
    for (int i = 0; i < 2; ++i) acc2[rt][i] = (f32x4){0.f, 0.f, 0.f, 0.f};
  #pragma unroll
  for (int ch = 0; ch < 4; ++ch) {     // B2 layout [ch4][tI8][ks2(2)][lane][8]
    #pragma unroll
    for (int ks2 = 0; ks2 < 2; ++ks2) {
      int ks = ch * 2 + ks2;
      bf16x8 u0 = *(const bf16x8*)&Us[c16][ks * 32 + kg * 8];
      bf16x8 u1 = *(const bf16x8*)&Us[16 + c16][ks * 32 + kg * 8];
      #pragma unroll
      for (int i = 0; i < 2; ++i) {
        int tI = wv * 2 + i;
        size_t boff = ((size_t)(ch * 16 + tI * 2 + ks2) * 64 + lane) * 8;
        bf16x8 bh = *(const bf16x8*)&B2h[boff];
        acc2[0][i] = __builtin_amdgcn_mfma_f32_16x16x32_bf16(u0, bh, acc2[0][i], 0, 0, 0);
        acc2[1][i] = __builtin_amdgcn_mfma_f32_16x16x32_bf16(u1, bh, acc2[1][i], 0, 0, 0);
      }
    }
  }
  {
    float bv[2], gv[2], bnv[2];
    #pragma unroll
    for (int i = 0; i < 2; ++i) {
      int c = (wv * 2 + i) * 16 + c16;
      bv[i] = b2[c]; gv[i] = gn[c]; bnv[i] = bn[c];
    }
    float xv[2][4][2];
    #pragma unroll
    for (int rt = 0; rt < 2; ++rt) {
      #pragma unroll
      for (int j = 0; j < 4; ++j) {
        int row = row0 + rt * 16 + kg * 4 + j;
        float a1 = 0.f, a2 = 0.f;
        #pragma unroll
        for (int i = 0; i < 2; ++i) {
          size_t p = (size_t)row * HH + (wv * 2 + i) * 16 + c16;
          float v = acc2[rt][i][j] + bv[i];
          if (!first) v += h[p];
          xv[rt][j][i] = v;
          h[p] = v;
          a1 += v; a2 = fmaf(v, v, a2);
        }
        #pragma unroll
        for (int m = 1; m <= 8; m <<= 1) { a1 += __shfl_xor(a1, m); a2 += __shfl_xor(a2, m); }
        if (c16 == 0) { red[wv][rt*16 + kg*4 + j][0] = a1; red[wv][rt*16 + kg*4 + j][1] = a2; }
      }
    }
    __syncthreads();
    #pragma unroll
    for (int rt = 0; rt < 2; ++rt) {
      #pragma unroll
      for (int j = 0; j < 4; ++j) {
        int row = rt * 16 + kg * 4 + j;
        float S1 = red[0][row][0] + red[1][row][0] + red[2][row][0] + red[3][row][0];
        float S2 = red[0][row][1] + red[1][row][1] + red[2][row][1] + red[3][row][1];
        float mu = S1 * (1.f / 128.f);
        float var = fmaxf(S2 * (1.f / 128.f) - mu * mu, 0.f);
        float rs = rsqrtf(var + LN_EPS_);
        #pragma unroll
        for (int i = 0; i < 2; ++i) {
          float o = fmaxf((xv[rt][j][i] - mu) * rs * gv[i] + bnv[i], 0.f);
          size_t p = (size_t)(row0 + row) * HH + (wv * 2 + i) * 16 + c16;
          hnb[p] = o;
          hb[p] = bf16_rne(o);
        }
      }
    }
  }
}

// ---------------- final output GEMM (Nx128 @ 128x16) ----------------
__global__ __launch_bounds__(256) void outgemm_kernel(const float* __restrict__ hn, const float* __restrict__ w,
                                                      const float* __restrict__ b, float* __restrict__ out) {
  __shared__ float Ws[HH * DOUT_];
  int tid = threadIdx.x;
  {
    const float4* s4 = (const float4*)w;
    float4* d4 = (float4*)Ws;
    d4[tid*2] = s4[tid*2]; d4[tid*2+1] = s4[tid*2+1];
  }
  __syncthreads();
  int id = blockIdx.x * 256 + tid;
  int n = id >> 4, c = id & 15;
  if (n >= NN) return;
  float s = b[c];
  const float* hr = &hn[(size_t)n*HH];
  #pragma unroll 8
  for (int k = 0; k < HH; ++k) s += hr[k] * Ws[k*DOUT_ + c];
  out[n*DOUT_ + c] = s;
}

extern "C" void kernel_launch(void* const* d_in, const int* in_sizes, int n_in,
                              void* d_out, int out_size, void* d_ws, size_t ws_size,
                              hipStream_t stream) {
  const float* x    = (const float*)d_in[0];
  const int*   ei   = (const int*)d_in[1];
  const float* eatt = (const float*)d_in[2];
  const float* enw  = (const float*)d_in[3];
  const float* enb  = (const float*)d_in[4];
  const float* eew  = (const float*)d_in[5];
  const float* eeb  = (const float*)d_in[6];
  const float* t    = (const float*)d_in[7];
  const float* m1w  = (const float*)d_in[8];
  const float* m1b  = (const float*)d_in[9];
  const float* mlg  = (const float*)d_in[10];
  const float* mlb  = (const float*)d_in[11];
  const float* m2w  = (const float*)d_in[12];
  const float* m2b  = (const float*)d_in[13];
  const float* lng  = (const float*)d_in[14];
  const float* lnb  = (const float*)d_in[15];
  const float* linw = (const float*)d_in[16];
  const float* linb = (const float*)d_in[17];
  float* out = (float*)d_out;

  char* ws = (char*)d_ws;
  size_t o = 0;
  auto take = [&](size_t bytes) { char* p = ws + o; o = (o + bytes + 255) & ~(size_t)255; return p; };
  int*    deg  = (int*)take((size_t)NN * 4);
  int*    off  = (int*)take((size_t)(NN + 1) * 4);
  int*    cur  = (int*)take((size_t)NN * 4);
  int*    srcs = (int*)take((size_t)EE * 4);
  float4* ea4  = (float4*)take((size_t)EE * 16);
  float*  h    = (float*)take((size_t)NN * HH * 4);
  float*  hnb  = (float*)take((size_t)NN * HH * 4);
  u16*    hb   = (u16*)take((size_t)NN * HH * 2);
  u16*    tmpH = (u16*)take((size_t)NN * HH * 2);
  u16*    tmpL = (u16*)take((size_t)NN * HH * 2);
  u16*    w1h  = (u16*)take((size_t)LL * HH * 256 * 2);
  u16*    w2h  = (u16*)take((size_t)LL * 256 * HH * 2);

  const int* src = ei;
  const int* dst = ei + EE;

  hipMemsetAsync(deg, 0, (size_t)NN * 4, stream);
  hist_kernel<<<(EE + 255) / 256, 256, 0, stream>>>(dst, deg);
  scan_kernel<<<1, 1024, 0, stream>>>(deg, off, cur);
  scatter_kernel<<<(EE + 255) / 256, 256, 0, stream>>>(src, dst, (const float4*)eatt, cur, srcs, ea4);
  int wblocks = (LL * HH * 256 / 8 + 255) / 256;   // 192
  wpack_kernel<<<wblocks, 256, 0, stream>>>(m1w, w1h, HH, 256, 1);   // [ch4][tI16][lane][8]
  wpack_kernel<<<wblocks, 256, 0, stream>>>(m2w, w2h, 256, HH, 2);   // [ch4][tI8][ks2][lane][8]
  encoder_kernel<<<(NN * 64 + 255) / 256, 256, 0, stream>>>(x, enw, enb, h, hb);

  int gblocks = NN / 32;   // 625
  for (int i = 0; i < LL; ++i) {
    const float* cin = (i == 0) ? h : hnb;
    conv_kernel<<<(NN + 3) / 4, 256, 0, stream>>>(cin, hb, off, srcs, ea4, eew, eeb, t, i, tmpH, tmpL);
    int nrm = (i + 1) % LL;  // layer i's output normed with ln params of layer i+1 (layer 0 for final norm)
    mlp_fused<<<gblocks, 256, 0, stream>>>(tmpH, tmpL,
                                           w1h + (size_t)i * 32768,
                                           m1b + i * 256, mlg + i * 256, mlb + i * 256,
                                           w2h + (size_t)i * 32768,
                                           m2b + i * HH, lng + nrm * HH, lnb + nrm * HH,
                                           h, hnb, hb, i == 0 ? 1 : 0);
  }
  outgemm_kernel<<<(NN * DOUT_ + 255) / 256, 256, 0, stream>>>(hnb, linw, linb, out);
}

// Round 18
// 843.445 us; speedup vs baseline: 1.1698x; 1.0509x over previous
//
#include <hip/hip_runtime.h>
#include <hip/hip_bf16.h>
#include <math.h>

#define NN 20000
#define EE 640000
#define HH 128
#define LL 12
#define DOUT_ 16
#define EPS_ 1e-7f
#define LN_EPS_ 1e-5f

typedef unsigned short u16;
typedef unsigned int u32;
typedef __attribute__((ext_vector_type(8))) short bf16x8;
typedef __attribute__((ext_vector_type(4))) float f32x4;

__device__ inline u16 bf16_rne(float v) {
  u32 u = __float_as_uint(v);
  return (u16)((u + 0x7FFFu + ((u >> 16) & 1u)) >> 16);
}
__device__ inline float bf16_tof(u16 h) { return __uint_as_float(((u32)h) << 16); }

// ---------------- CSR build ----------------
__global__ __launch_bounds__(256) void hist_kernel(const int* __restrict__ dst, int* __restrict__ deg) {
  int e = blockIdx.x * 256 + threadIdx.x;
  if (e < EE) atomicAdd(&deg[dst[e]], 1);
}

__global__ __launch_bounds__(1024) void scan_kernel(const int* __restrict__ deg, int* __restrict__ off,
                                                    int* __restrict__ cur) {
  __shared__ int part[1024];
  int tid = threadIdx.x;
  const int CH = (NN + 1023) >> 10;   // 20
  int base = tid * CH;
  int s = 0;
  for (int j = 0; j < CH; ++j) { int i = base + j; if (i < NN) s += deg[i]; }
  part[tid] = s;
  __syncthreads();
  for (int d = 1; d < 1024; d <<= 1) {
    int v = (tid >= d) ? part[tid - d] : 0;
    __syncthreads();
    part[tid] += v;
    __syncthreads();
  }
  int run = part[tid] - s;  // exclusive prefix
  for (int j = 0; j < CH; ++j) {
    int i = base + j;
    if (i < NN) { off[i] = run; cur[i] = run; run += deg[i]; }
  }
  if (tid == 1023) off[NN] = part[1023];
}

__global__ __launch_bounds__(256) void scatter_kernel(const int* __restrict__ src, const int* __restrict__ dst,
                                                      const float4* __restrict__ ea, int* __restrict__ cur,
                                                      int* __restrict__ srcs, float4* __restrict__ ea4) {
  int e = blockIdx.x * 256 + threadIdx.x;
  if (e >= EE) return;
  int d = dst[e];
  int p = atomicAdd(&cur[d], 1);
  srcs[p] = src[e];
  ea4[p] = ea[e];
}

// ---------------- weight pack: fp32 [L][K][N] -> bf16 (hi only) MFMA-fragment order ----------------
// layout: [l][chunk][tI(N/16)][ks2(KSC)][lane(64)][j(8)]; k = (chunk*KSC+ks2)*32 + (lane>>4)*8 + j
__global__ __launch_bounds__(256) void wpack_kernel(const float* __restrict__ w, u16* __restrict__ dh,
                                                    int K, int N, int KSC) {
  int fid = blockIdx.x * 256 + threadIdx.x;
  int perL = (K * N) >> 3;
  if (fid >= LL * perL) return;
  int l = fid / perL, r = fid % perL;
  int lane = r & 63;
  int r2 = r >> 6;
  int ks2 = r2 % KSC; r2 /= KSC;
  int NT = N >> 4;
  int tI = r2 % NT;
  int chunk = r2 / NT;
  int c16 = lane & 15, kg = lane >> 4;
  int n = tI * 16 + c16;
  int k0 = (chunk * KSC + ks2) * 32 + kg * 8;
  const float* ws = w + (size_t)l * K * N;
  u16* oh = dh + (size_t)fid * 8;
  #pragma unroll
  for (int j = 0; j < 8; ++j) {
    oh[j] = bf16_rne(ws[(size_t)(k0 + j) * N + n]);
  }
}

// ---------------- encoder: h fp32 + hb bf16 plane ----------------
__global__ __launch_bounds__(256) void encoder_kernel(const float* __restrict__ x, const float* __restrict__ w,
                                                      const float* __restrict__ b, float* __restrict__ h,
                                                      u16* __restrict__ hb) {
  int id = blockIdx.x * 256 + threadIdx.x;
  if (id >= NN * 64) return;
  int n = id >> 6, cp = id & 63;
  int c0 = cp * 2;
  float x0 = x[n*3+0], x1 = x[n*3+1], x2 = x[n*3+2];
  float vx = b[c0]   + x0*w[c0]   + x1*w[HH+c0]   + x2*w[2*HH+c0];
  float vy = b[c0+1] + x0*w[c0+1] + x1*w[HH+c0+1] + x2*w[2*HH+c0+1];
  *(float2*)&h[(size_t)n*HH + c0] = make_float2(vx, vy);
  *(u32*)&hb[(size_t)n*HH + c0] = (u32)bf16_rne(vx) | ((u32)bf16_rne(vy) << 16);
}

// ---------------- GENConv aggregation: wave per dst node (round-12 proven form) ----------------
__global__ __launch_bounds__(256) void conv_kernel(const float* __restrict__ hn,
                                                   const u16* __restrict__ hb,
                                                   const int* __restrict__ off,
                                                   const int* __restrict__ srcs, const float4* __restrict__ ea4,
                                                   const float* __restrict__ eew, const float* __restrict__ eeb,
                                                   const float* __restrict__ t, int layer,
                                                   u16* __restrict__ tmpH, u16* __restrict__ tmpL) {
  int wid = blockIdx.x * 4 + (threadIdx.x >> 6);
  int lane = threadIdx.x & 63;
  if (wid >= NN) return;
  int c0 = lane * 2;
  float ti = t[layer];
  float w0x = eew[c0],      w0y = eew[c0+1];
  float w1x = eew[HH+c0],   w1y = eew[HH+c0+1];
  float w2x = eew[2*HH+c0], w2y = eew[2*HH+c0+1];
  float w3x = eew[3*HH+c0], w3y = eew[3*HH+c0+1];
  float bx = eeb[c0], by = eeb[c0+1];
  int e0 = off[wid], e1 = off[wid+1];
  float2 hd = *(const float2*)&hn[(size_t)wid*HH + c0];
  float den0 = 0.f, den1 = 0.f, num0 = 0.f, num1 = 0.f;

  int e = e0;
  const int UF = 8;
  for (; e + UF <= e1; e += UF) {
    int si[UF]; float4 av[UF];
    #pragma unroll
    for (int u = 0; u < UF; ++u) { si[u] = srcs[e + u]; av[u] = ea4[e + u]; }
    u32 hv[UF];
    #pragma unroll
    for (int u = 0; u < UF; ++u) hv[u] = *(const u32*)&hb[((u32)si[u] << 7) + c0];
    #pragma unroll
    for (int u = 0; u < UF; ++u) {
      float hx = bf16_tof((u16)(hv[u] & 0xffffu));
      float hy = bf16_tof((u16)(hv[u] >> 16));
      float eax = fmaf(av[u].w, w3x, fmaf(av[u].z, w2x, fmaf(av[u].y, w1x, fmaf(av[u].x, w0x, bx))));
      float eay = fmaf(av[u].w, w3y, fmaf(av[u].z, w2y, fmaf(av[u].y, w1y, fmaf(av[u].x, w0y, by))));
      float m0 = fmaxf(hx + eax, 0.f) + EPS_;
      float m1 = fmaxf(hy + eay, 0.f) + EPS_;
      float p0 = __expf(m0 * ti);
      float p1 = __expf(m1 * ti);
      den0 += p0; den1 += p1;
      num0 = fmaf(m0, p0, num0);
      num1 = fmaf(m1, p1, num1);
    }
  }
  for (; e < e1; ++e) {
    int sidx = srcs[e];
    float4 a = ea4[e];
    u32 hv = *(const u32*)&hb[((u32)sidx << 7) + c0];
    float hx = bf16_tof((u16)(hv & 0xffffu));
    float hy = bf16_tof((u16)(hv >> 16));
    float eax = fmaf(a.w, w3x, fmaf(a.z, w2x, fmaf(a.y, w1x, fmaf(a.x, w0x, bx))));
    float eay = fmaf(a.w, w3y, fmaf(a.z, w2y, fmaf(a.y, w1y, fmaf(a.x, w0y, by))));
    float m0 = fmaxf(hx + eax, 0.f) + EPS_;
    float m1 = fmaxf(hy + eay, 0.f) + EPS_;
    float p0 = __expf(m0 * ti);
    float p1 = __expf(m1 * ti);
    den0 += p0; den1 += p1;
    num0 = fmaf(m0, p0, num0);
    num1 = fmaf(m1, p1, num1);
  }
  float v0 = num0 / (den0 + 1e-16f) + hd.x;
  float v1 = num1 / (den1 + 1e-16f) + hd.y;
  u16 h0 = bf16_rne(v0), h1 = bf16_rne(v1);
  u16 l0 = bf16_rne(v0 - bf16_tof(h0)), l1 = bf16_rne(v1 - bf16_tof(h1));
  *(u32*)&tmpH[(size_t)wid*HH + c0] = (u32)h0 | ((u32)h1 << 16);
  *(u32*)&tmpL[(size_t)wid*HH + c0] = (u32)l0 | ((u32)l1 << 16);
}

// ---------------- fused MLP: GEMM1 + LN(256) + ReLU -> LDS -> GEMM2 + residual + LN(128) ----------------
// block = 16 rows, 4 waves. GEMM1: wave owns 64 cols, 2 MFMA per frag (A hi/lo split x plain-bf16 W1).
// U tile (16x256 bf16) lives in LDS only. GEMM2: wave owns 32 cols, 1 MFMA per frag
// (plain U x plain-bf16 W2). W planes read direct from L2 (packed fragment order).
__global__ __launch_bounds__(256) void mlp_fused(const u16* __restrict__ Ah, const u16* __restrict__ Al,
                                                 const u16* __restrict__ B1h,
                                                 const float* __restrict__ b1,
                                                 const float* __restrict__ g1, const float* __restrict__ bb1,
                                                 const u16* __restrict__ B2h,
                                                 const float* __restrict__ b2,
                                                 const float* __restrict__ gn, const float* __restrict__ bn,
                                                 float* __restrict__ h, float* __restrict__ hnb,
                                                 u16* __restrict__ hb, int first) {
  __shared__ u16 Us[16][264];          // 16x256 U tile, row pad 8 u16 (2-way LDS aliasing = free)
  __shared__ float red[4][16][2];
  int tid = threadIdx.x;
  int wv = tid >> 6, lane = tid & 63;
  int c16 = lane & 15, kg = lane >> 4;
  int row0 = blockIdx.x * 16;          // NN % 16 == 0

  // ---- GEMM1 ----
  const u16* pAh = Ah + (size_t)(row0 + c16) * HH + kg * 8;
  const u16* pAl = Al + (size_t)(row0 + c16) * HH + kg * 8;
  bf16x8 ah[4], al[4];
  #pragma unroll
  for (int ks = 0; ks < 4; ++ks) {
    ah[ks] = *(const bf16x8*)(pAh + ks * 32);
    al[ks] = *(const bf16x8*)(pAl + ks * 32);
  }
  f32x4 acc[4];
  #pragma unroll
  for (int i = 0; i < 4; ++i) acc[i] = (f32x4){0.f, 0.f, 0.f, 0.f};
  #pragma unroll
  for (int ch = 0; ch < 4; ++ch) {     // B1 layout [ch4][tI16][lane][8]
    #pragma unroll
    for (int i = 0; i < 4; ++i) {
      int tI = wv * 4 + i;
      size_t boff = ((size_t)(ch * 16 + tI) * 64 + lane) * 8;
      bf16x8 bh = *(const bf16x8*)&B1h[boff];
      acc[i] = __builtin_amdgcn_mfma_f32_16x16x32_bf16(ah[ch], bh, acc[i], 0, 0, 0);
      acc[i] = __builtin_amdgcn_mfma_f32_16x16x32_bf16(al[ch], bh, acc[i], 0, 0, 0);
    }
  }
  {
    float bv[4], gv[4], bbv[4];
    #pragma unroll
    for (int i = 0; i < 4; ++i) {
      int c = (wv * 4 + i) * 16 + c16;
      bv[i] = b1[c]; gv[i] = g1[c]; bbv[i] = bb1[c];
    }
    float xv[4][4], s1[4], s2[4];
    #pragma unroll
    for (int j = 0; j < 4; ++j) {
      float a1 = 0.f, a2 = 0.f;
      #pragma unroll
      for (int i = 0; i < 4; ++i) {
        float v = acc[i][j] + bv[i];
        xv[j][i] = v; a1 += v; a2 = fmaf(v, v, a2);
      }
      #pragma unroll
      for (int m = 1; m <= 8; m <<= 1) { a1 += __shfl_xor(a1, m); a2 += __shfl_xor(a2, m); }
      s1[j] = a1; s2[j] = a2;
    }
    if (c16 == 0) {
      #pragma unroll
      for (int j = 0; j < 4; ++j) { red[wv][kg*4+j][0] = s1[j]; red[wv][kg*4+j][1] = s2[j]; }
    }
    __syncthreads();
    #pragma unroll
    for (int j = 0; j < 4; ++j) {
      int row = kg * 4 + j;
      float S1 = red[0][row][0] + red[1][row][0] + red[2][row][0] + red[3][row][0];
      float S2 = red[0][row][1] + red[1][row][1] + red[2][row][1] + red[3][row][1];
      float mu = S1 * (1.f / 256.f);
      float var = fmaxf(S2 * (1.f / 256.f) - mu * mu, 0.f);
      float rs = rsqrtf(var + LN_EPS_);
      #pragma unroll
      for (int i = 0; i < 4; ++i) {
        float o = fmaxf((xv[j][i] - mu) * rs * gv[i] + bbv[i], 0.f);
        Us[row][(wv * 4 + i) * 16 + c16] = bf16_rne(o);
      }
    }
  }
  __syncthreads();

  // ---- GEMM2 ----
  bf16x8 ua[8];
  #pragma unroll
  for (int ks = 0; ks < 8; ++ks) ua[ks] = *(const bf16x8*)&Us[c16][ks * 32 + kg * 8];
  f32x4 acc2[2];
  #pragma unroll
  for (int i = 0; i < 2; ++i) acc2[i] = (f32x4){0.f, 0.f, 0.f, 0.f};
  #pragma unroll
  for (int ch = 0; ch < 4; ++ch) {     // B2 layout [ch4][tI8][ks2(2)][lane][8]
    #pragma unroll
    for (int ks2 = 0; ks2 < 2; ++ks2) {
      int ks = ch * 2 + ks2;
      #pragma unroll
      for (int i = 0; i < 2; ++i) {
        int tI = wv * 2 + i;
        size_t boff = ((size_t)(ch * 16 + tI * 2 + ks2) * 64 + lane) * 8;
        bf16x8 bh = *(const bf16x8*)&B2h[boff];
        acc2[i] = __builtin_amdgcn_mfma_f32_16x16x32_bf16(ua[ks], bh, acc2[i], 0, 0, 0);
      }
    }
  }
  {
    float bv[2], gv[2], bnv[2];
    #pragma unroll
    for (int i = 0; i < 2; ++i) {
      int c = (wv * 2 + i) * 16 + c16;
      bv[i] = b2[c]; gv[i] = gn[c]; bnv[i] = bn[c];
    }
    float xv[4][2], s1[4], s2[4];
    #pragma unroll
    for (int j = 0; j < 4; ++j) {
      int row = row0 + kg * 4 + j;
      float a1 = 0.f, a2 = 0.f;
      #pragma unroll
      for (int i = 0; i < 2; ++i) {
        size_t p = (size_t)row * HH + (wv * 2 + i) * 16 + c16;
        float v = acc2[i][j] + bv[i];
        if (!first) v += h[p];
        xv[j][i] = v;
        h[p] = v;
        a1 += v; a2 = fmaf(v, v, a2);
      }
      #pragma unroll
      for (int m = 1; m <= 8; m <<= 1) { a1 += __shfl_xor(a1, m); a2 += __shfl_xor(a2, m); }
      s1[j] = a1; s2[j] = a2;
    }
    if (c16 == 0) {
      #pragma unroll
      for (int j = 0; j < 4; ++j) { red[wv][kg*4+j][0] = s1[j]; red[wv][kg*4+j][1] = s2[j]; }
    }
    __syncthreads();
    #pragma unroll
    for (int j = 0; j < 4; ++j) {
      int row = kg * 4 + j;
      float S1 = red[0][row][0] + red[1][row][0] + red[2][row][0] + red[3][row][0];
      float S2 = red[0][row][1] + red[1][row][1] + red[2][row][1] + red[3][row][1];
      float mu = S1 * (1.f / 128.f);
      float var = fmaxf(S2 * (1.f / 128.f) - mu * mu, 0.f);
      float rs = rsqrtf(var + LN_EPS_);
      #pragma unroll
      for (int i = 0; i < 2; ++i) {
        float o = fmaxf((xv[j][i] - mu) * rs * gv[i] + bnv[i], 0.f);
        size_t p = (size_t)(row0 + row) * HH + (wv * 2 + i) * 16 + c16;
        hnb[p] = o;
        hb[p] = bf16_rne(o);
      }
    }
  }
}

// ---------------- final output GEMM (Nx128 @ 128x16) ----------------
__global__ __launch_bounds__(256) void outgemm_kernel(const float* __restrict__ hn, const float* __restrict__ w,
                                                      const float* __restrict__ b, float* __restrict__ out) {
  __shared__ float Ws[HH * DOUT_];
  int tid = threadIdx.x;
  {
    const float4* s4 = (const float4*)w;
    float4* d4 = (float4*)Ws;
    d4[tid*2] = s4[tid*2]; d4[tid*2+1] = s4[tid*2+1];
  }
  __syncthreads();
  int id = blockIdx.x * 256 + tid;
  int n = id >> 4, c = id & 15;
  if (n >= NN) return;
  float s = b[c];
  const float* hr = &hn[(size_t)n*HH];
  #pragma unroll 8
  for (int k = 0; k < HH; ++k) s += hr[k] * Ws[k*DOUT_ + c];
  out[n*DOUT_ + c] = s;
}

extern "C" void kernel_launch(void* const* d_in, const int* in_sizes, int n_in,
                              void* d_out, int out_size, void* d_ws, size_t ws_size,
                              hipStream_t stream) {
  const float* x    = (const float*)d_in[0];
  const int*   ei   = (const int*)d_in[1];
  const float* eatt = (const float*)d_in[2];
  const float* enw  = (const float*)d_in[3];
  const float* enb  = (const float*)d_in[4];
  const float* eew  = (const float*)d_in[5];
  const float* eeb  = (const float*)d_in[6];
  const float* t    = (const float*)d_in[7];
  const float* m1w  = (const float*)d_in[8];
  const float* m1b  = (const float*)d_in[9];
  const float* mlg  = (const float*)d_in[10];
  const float* mlb  = (const float*)d_in[11];
  const float* m2w  = (const float*)d_in[12];
  const float* m2b  = (const float*)d_in[13];
  const float* lng  = (const float*)d_in[14];
  const float* lnb  = (const float*)d_in[15];
  const float* linw = (const float*)d_in[16];
  const float* linb = (const float*)d_in[17];
  float* out = (float*)d_out;

  char* ws = (char*)d_ws;
  size_t o = 0;
  auto take = [&](size_t bytes) { char* p = ws + o; o = (o + bytes + 255) & ~(size_t)255; return p; };
  int*    deg  = (int*)take((size_t)NN * 4);
  int*    off  = (int*)take((size_t)(NN + 1) * 4);
  int*    cur  = (int*)take((size_t)NN * 4);
  int*    srcs = (int*)take((size_t)EE * 4);
  float4* ea4  = (float4*)take((size_t)EE * 16);
  float*  h    = (float*)take((size_t)NN * HH * 4);
  float*  hnb  = (float*)take((size_t)NN * HH * 4);
  u16*    hb   = (u16*)take((size_t)NN * HH * 2);
  u16*    tmpH = (u16*)take((size_t)NN * HH * 2);
  u16*    tmpL = (u16*)take((size_t)NN * HH * 2);
  u16*    w1h  = (u16*)take((size_t)LL * HH * 256 * 2);
  u16*    w2h  = (u16*)take((size_t)LL * 256 * HH * 2);

  const int* src = ei;
  const int* dst = ei + EE;

  hipMemsetAsync(deg, 0, (size_t)NN * 4, stream);
  hist_kernel<<<(EE + 255) / 256, 256, 0, stream>>>(dst, deg);
  scan_kernel<<<1, 1024, 0, stream>>>(deg, off, cur);
  scatter_kernel<<<(EE + 255) / 256, 256, 0, stream>>>(src, dst, (const float4*)eatt, cur, srcs, ea4);
  int wblocks = (LL * HH * 256 / 8 + 255) / 256;   // 192
  wpack_kernel<<<wblocks, 256, 0, stream>>>(m1w, w1h, HH, 256, 1);   // [ch4][tI16][lane][8]
  wpack_kernel<<<wblocks, 256, 0, stream>>>(m2w, w2h, 256, HH, 2);   // [ch4][tI8][ks2][lane][8]
  encoder_kernel<<<(NN * 64 + 255) / 256, 256, 0, stream>>>(x, enw, enb, h, hb);

  int gblocks = NN / 16;   // 1250
  for (int i = 0; i < LL; ++i) {
    const float* cin = (i == 0) ? h : hnb;
    conv_kernel<<<(NN + 3) / 4, 256, 0, stream>>>(cin, hb, off, srcs, ea4, eew, eeb, t, i, tmpH, tmpL);
    int nrm = (i + 1) % LL;  // layer i's output normed with ln params of layer i+1 (layer 0 for final norm)
    mlp_fused<<<gblocks, 256, 0, stream>>>(tmpH, tmpL,
                                           w1h + (size_t)i * 32768,
                                           m1b + i * 256, mlg + i * 256, mlb + i * 256,
                                           w2h + (size_t)i * 32768,
                                           m2b + i * HH, lng + nrm * HH, lnb + nrm * HH,
                                           h, hnb, hb, i == 0 ? 1 : 0);
  }
  outgemm_kernel<<<(NN * DOUT_ + 255) / 256, 256, 0, stream>>>(hnb, linw, linb, out);
}